// Round 7
// baseline (256.148 us; speedup 1.0000x reference)
//
#include <hip/hip_runtime.h>
#include <stdint.h>

#define NNODES 200000
#define BNODES 40000
#define DEG    16
#define DFEAT  128
#define DOUT   256
#define NCLS   128
#define TILE   16   // nodes per MLP block

typedef __attribute__((ext_vector_type(8))) __bf16 bf16x8;
typedef __attribute__((ext_vector_type(4))) float  floatx4;

// round-to-nearest-even fp32 -> bf16 bits
__device__ __forceinline__ uint32_t f2bf(float f) {
  uint32_t x = __float_as_uint(f);
  return ((x + 0x7fffu + ((x >> 16) & 1u)) >> 16) & 0xffffu;
}

__global__ __launch_bounds__(256) void cvt_weights(
    const float* __restrict__ W1, const float* __restrict__ W3,
    uint16_t* __restrict__ w1b, uint16_t* __restrict__ w3b) {
  int i = blockIdx.x * 256 + threadIdx.x;
  if (i < DOUT * 2 * DFEAT) w1b[i] = (uint16_t)f2bf(W1[i]);
  if (i < NCLS * DOUT)      w3b[i] = (uint16_t)f2bf(W3[i]);
}

// ---------------------------------------------------------------------------
// Pure gather kernel: no LDS, no barriers, no MFMA. Every wave continuously
// issues full-wave row loads (64 lanes x float2 = one 512B fp32 feature row
// per VMEM instruction, SGPR row base). Lane owns dims 2l,2l+1 -> the
// segment-mean is 16 in-lane float2 adds, zero cross-lane ops. 17 loads
// (8.7 KB) in flight per wave x 32 waves/CU. Output emb row: [self(128 bf16)
// | mean(128 bf16)] -- bit-identical to the fused r1 path.
// ---------------------------------------------------------------------------
__global__ __launch_bounds__(256, 8) void gather_mean(
    const int* __restrict__ inputs, const int* __restrict__ nbr,
    const float* __restrict__ feat, uint16_t* __restrict__ emb) {
  const int w    = __builtin_amdgcn_readfirstlane(threadIdx.x >> 6);  // wave 0..3
  const int lane = threadIdx.x & 63;
  const int waveId = blockIdx.x * 4 + w;        // 0..9999
  const float* fb = feat + lane * 2;            // dims 2l, 2l+1
#pragma unroll
  for (int p = 0; p < 4; ++p) {
    const int node = waveId * 4 + p;            // 0..39999
    const int* nb  = nbr + node * DEG;          // wave-uniform -> s_load
    const int self = inputs[node];
    float2 r[16];
#pragma unroll
    for (int j = 0; j < 16; ++j)
      r[j] = *(const float2*)(fb + (size_t)nb[j] * DFEAT);
    const float2 sv = *(const float2*)(fb + (size_t)self * DFEAT);
    const float sx = (((r[0].x + r[1].x) + (r[2].x + r[3].x)) + ((r[4].x + r[5].x) + (r[6].x + r[7].x)))
                   + (((r[8].x + r[9].x) + (r[10].x + r[11].x)) + ((r[12].x + r[13].x) + (r[14].x + r[15].x)));
    const float sy = (((r[0].y + r[1].y) + (r[2].y + r[3].y)) + ((r[4].y + r[5].y) + (r[6].y + r[7].y)))
                   + (((r[8].y + r[9].y) + (r[10].y + r[11].y)) + ((r[12].y + r[13].y) + (r[14].y + r[15].y)));
    uint16_t* er = emb + (size_t)node * (2 * DFEAT);
    *(uint32_t*)(er + lane * 2)         = f2bf(sv.x) | (f2bf(sv.y) << 16);
    *(uint32_t*)(er + DFEAT + lane * 2) = f2bf(sx * 0.0625f) | (f2bf(sy * 0.0625f) << 16);
  }
}

// ---------------------------------------------------------------------------
// MLP kernel: stage emb tile (coalesced 8 KB), then the proven phases 2-4.
// ---------------------------------------------------------------------------
__global__ __launch_bounds__(256, 8) void sage_mlp(
    const uint16_t* __restrict__ emb,
    const uint16_t* __restrict__ w1b, const float* __restrict__ b1,
    const uint16_t* __restrict__ w3b, const float* __restrict__ b3,
    float* __restrict__ out) {
  __shared__ __align__(16) unsigned char smemA[TILE * 264 * 2];   // 8448 B
  __shared__ __align__(16) uint16_t hL[TILE][264];                // 8448 B
  uint16_t (*embL)[264] = (uint16_t (*)[264])smemA;
  float    (*lgL)[132]  = (float    (*)[132])smemA;

  const int tid  = threadIdx.x;
  const int w    = __builtin_amdgcn_readfirstlane(tid >> 6);   // wave 0..3
  const int lane = tid & 63;
  const int quad = lane >> 4;
  const int l16  = lane & 15;

  // ---------------- Phase 1': stage emb tile from workspace ---------------
  {
    const int r = tid >> 4;          // row 0..15
    const int c = tid & 15;          // 32-B chunk 0..15
    const uint16_t* er = emb + ((size_t)(blockIdx.x * TILE + r)) * (2 * DFEAT) + c * 16;
    const uint4 v0 = *(const uint4*)(er + 0);
    const uint4 v1 = *(const uint4*)(er + 8);
    *(uint4*)&embL[r][c * 16 + 0] = v0;
    *(uint4*)&embL[r][c * 16 + 8] = v1;
  }
  __syncthreads();

  const int kq = quad * 8;

  // ---------------- Phase 2: h = relu(emb @ W1^T + b1), bf16 -> LDS --------
  // M=16 rows; wave w owns output cols w*64 .. w*64+63
  {
    floatx4 acc[4];
#pragma unroll
    for (int ot = 0; ot < 4; ++ot) {
      floatx4 z = {0.f, 0.f, 0.f, 0.f};
      acc[ot] = z;
    }
#pragma unroll
    for (int kt = 0; kt < 8; ++kt) {
      const int k0 = kt * 32 + kq;
      const bf16x8 a = *(const bf16x8*)&embL[l16][k0];
#pragma unroll
      for (int ot = 0; ot < 4; ++ot) {
        const int o = w * 64 + ot * 16 + l16;
        const bf16x8 b = *(const bf16x8*)(w1b + o * 256 + k0);
        acc[ot] = __builtin_amdgcn_mfma_f32_16x16x32_bf16(a, b, acc[ot], 0, 0, 0);
      }
    }
#pragma unroll
    for (int ot = 0; ot < 4; ++ot) {
      const int o = w * 64 + ot * 16 + l16;
      const float bias = b1[o];
#pragma unroll
      for (int r = 0; r < 4; ++r) {
        float v = acc[ot][r] + bias;
        v = fmaxf(v, 0.f);
        hL[quad * 4 + r][o] = (uint16_t)f2bf(v);
      }
    }
  }
  __syncthreads();

  // ---------------- Phase 3: logits = h @ W3^T + b3 -> LDS fp32 ------------
  {
    floatx4 acc2[2];
#pragma unroll
    for (int ct = 0; ct < 2; ++ct) {
      floatx4 z = {0.f, 0.f, 0.f, 0.f};
      acc2[ct] = z;
    }
#pragma unroll
    for (int kt = 0; kt < 8; ++kt) {
      const int k0 = kt * 32 + kq;
      const bf16x8 a = *(const bf16x8*)&hL[l16][k0];
#pragma unroll
      for (int ct = 0; ct < 2; ++ct) {
        const int c = w * 32 + ct * 16 + l16;
        const bf16x8 b = *(const bf16x8*)(w3b + c * 256 + k0);
        acc2[ct] = __builtin_amdgcn_mfma_f32_16x16x32_bf16(a, b, acc2[ct], 0, 0, 0);
      }
    }
#pragma unroll
    for (int ct = 0; ct < 2; ++ct) {
      const int c = w * 32 + ct * 16 + l16;
      const float bias = b3[c];
#pragma unroll
      for (int r = 0; r < 4; ++r)
        lgL[quad * 4 + r][c] = acc2[ct][r] + bias;
    }
  }
  __syncthreads();

  // ---------------- Phase 4: row L2-normalize + store ----------------------
  {
    const int nr  = tid >> 4;       // node row 0..15
    const int sub = tid & 15;       // 16 threads per row, 8 cols each
    const float* lrow = &lgL[nr][sub * 8];
    float4 v0 = *(const float4*)(lrow + 0);
    float4 v1 = *(const float4*)(lrow + 4);
    float ss = v0.x * v0.x + v0.y * v0.y + v0.z * v0.z + v0.w * v0.w
             + v1.x * v1.x + v1.y * v1.y + v1.z * v1.z + v1.w * v1.w;
    ss += __shfl_xor(ss, 1);
    ss += __shfl_xor(ss, 2);
    ss += __shfl_xor(ss, 4);
    ss += __shfl_xor(ss, 8);
    const float scale = 1.f / fmaxf(sqrtf(ss), 1e-12f);
    v0.x *= scale; v0.y *= scale; v0.z *= scale; v0.w *= scale;
    v1.x *= scale; v1.y *= scale; v1.z *= scale; v1.w *= scale;
    float* op = out + ((size_t)(blockIdx.x * TILE + nr)) * NCLS + sub * 8;
    *(float4*)(op + 0) = v0;
    *(float4*)(op + 4) = v1;
  }
}

// ---------------------------------------------------------------------------
// Fused fallback (workspace too small for emb buffer): r1-style fp32 gather
// ---------------------------------------------------------------------------
__global__ __launch_bounds__(256, 8) void sage_fused_fb(
    const int* __restrict__ inputs, const int* __restrict__ nbr,
    const float* __restrict__ feat,
    const uint16_t* __restrict__ w1b, const float* __restrict__ b1,
    const uint16_t* __restrict__ w3b, const float* __restrict__ b3,
    float* __restrict__ out) {
  __shared__ __align__(16) unsigned char smemA[TILE * 264 * 2];
  __shared__ __align__(16) uint16_t hL[TILE][264];
  uint16_t (*embL)[264] = (uint16_t (*)[264])smemA;
  float    (*lgL)[132]  = (float    (*)[132])smemA;

  const int tid  = threadIdx.x;
  const int w    = __builtin_amdgcn_readfirstlane(tid >> 6);
  const int lane = tid & 63;
  const int quad = lane >> 4;
  const int l16  = lane & 15;

  {
    const int nodeBase = blockIdx.x * TILE + w * 4;
    const float* fb = feat + lane * 2;
#pragma unroll
    for (int p = 0; p < 4; ++p) {
      const int node = nodeBase + p;
      const int* nb  = nbr + node * DEG;
      const int self = inputs[node];
      float2 r[16];
#pragma unroll
      for (int j = 0; j < 16; ++j)
        r[j] = *(const float2*)(fb + (size_t)nb[j] * DFEAT);
      const float2 sv = *(const float2*)(fb + (size_t)self * DFEAT);
      const float sx = (((r[0].x + r[1].x) + (r[2].x + r[3].x)) + ((r[4].x + r[5].x) + (r[6].x + r[7].x)))
                     + (((r[8].x + r[9].x) + (r[10].x + r[11].x)) + ((r[12].x + r[13].x) + (r[14].x + r[15].x)));
      const float sy = (((r[0].y + r[1].y) + (r[2].y + r[3].y)) + ((r[4].y + r[5].y) + (r[6].y + r[7].y)))
                     + (((r[8].y + r[9].y) + (r[10].y + r[11].y)) + ((r[12].y + r[13].y) + (r[14].y + r[15].y)));
      const int row = w * 4 + p;
      *(uint32_t*)&embL[row][lane * 2]         = f2bf(sv.x) | (f2bf(sv.y) << 16);
      *(uint32_t*)&embL[row][DFEAT + lane * 2] = f2bf(sx * 0.0625f) | (f2bf(sy * 0.0625f) << 16);
    }
  }
  __syncthreads();

  const int kq = quad * 8;
  {
    floatx4 acc[4];
#pragma unroll
    for (int ot = 0; ot < 4; ++ot) {
      floatx4 z = {0.f, 0.f, 0.f, 0.f};
      acc[ot] = z;
    }
#pragma unroll
    for (int kt = 0; kt < 8; ++kt) {
      const int k0 = kt * 32 + kq;
      const bf16x8 a = *(const bf16x8*)&embL[l16][k0];
#pragma unroll
      for (int ot = 0; ot < 4; ++ot) {
        const int o = w * 64 + ot * 16 + l16;
        const bf16x8 b = *(const bf16x8*)(w1b + o * 256 + k0);
        acc[ot] = __builtin_amdgcn_mfma_f32_16x16x32_bf16(a, b, acc[ot], 0, 0, 0);
      }
    }
#pragma unroll
    for (int ot = 0; ot < 4; ++ot) {
      const int o = w * 64 + ot * 16 + l16;
      const float bias = b1[o];
#pragma unroll
      for (int r = 0; r < 4; ++r) {
        float v = acc[ot][r] + bias;
        v = fmaxf(v, 0.f);
        hL[quad * 4 + r][o] = (uint16_t)f2bf(v);
      }
    }
  }
  __syncthreads();
  {
    floatx4 acc2[2];
#pragma unroll
    for (int ct = 0; ct < 2; ++ct) {
      floatx4 z = {0.f, 0.f, 0.f, 0.f};
      acc2[ct] = z;
    }
#pragma unroll
    for (int kt = 0; kt < 8; ++kt) {
      const int k0 = kt * 32 + kq;
      const bf16x8 a = *(const bf16x8*)&hL[l16][k0];
#pragma unroll
      for (int ct = 0; ct < 2; ++ct) {
        const int c = w * 32 + ct * 16 + l16;
        const bf16x8 b = *(const bf16x8*)(w3b + c * 256 + k0);
        acc2[ct] = __builtin_amdgcn_mfma_f32_16x16x32_bf16(a, b, acc2[ct], 0, 0, 0);
      }
    }
#pragma unroll
    for (int ct = 0; ct < 2; ++ct) {
      const int c = w * 32 + ct * 16 + l16;
      const float bias = b3[c];
#pragma unroll
      for (int r = 0; r < 4; ++r)
        lgL[quad * 4 + r][c] = acc2[ct][r] + bias;
    }
  }
  __syncthreads();
  {
    const int nr  = tid >> 4;
    const int sub = tid & 15;
    const float* lrow = &lgL[nr][sub * 8];
    float4 v0 = *(const float4*)(lrow + 0);
    float4 v1 = *(const float4*)(lrow + 4);
    float ss = v0.x * v0.x + v0.y * v0.y + v0.z * v0.z + v0.w * v0.w
             + v1.x * v1.x + v1.y * v1.y + v1.z * v1.z + v1.w * v1.w;
    ss += __shfl_xor(ss, 1);
    ss += __shfl_xor(ss, 2);
    ss += __shfl_xor(ss, 4);
    ss += __shfl_xor(ss, 8);
    const float scale = 1.f / fmaxf(sqrtf(ss), 1e-12f);
    v0.x *= scale; v0.y *= scale; v0.z *= scale; v0.w *= scale;
    v1.x *= scale; v1.y *= scale; v1.z *= scale; v1.w *= scale;
    float* op = out + ((size_t)(blockIdx.x * TILE + nr)) * NCLS + sub * 8;
    *(float4*)(op + 0) = v0;
    *(float4*)(op + 4) = v1;
  }
}

extern "C" void kernel_launch(void* const* d_in, const int* in_sizes, int n_in,
                              void* d_out, int out_size, void* d_ws, size_t ws_size,
                              hipStream_t stream) {
  const int*   inputs = (const int*)d_in[0];
  const int*   nbr    = (const int*)d_in[1];
  // d_in[2] segment_ids: regular repeat(arange(B), 16) -> implicit, unused
  const float* feat   = (const float*)d_in[3];
  const float* W1     = (const float*)d_in[4];
  const float* b1     = (const float*)d_in[5];
  const float* W3     = (const float*)d_in[6];
  const float* b3     = (const float*)d_in[7];

  uint16_t* w1b = (uint16_t*)d_ws;                 // 256*256 bf16 = 128 KiB
  uint16_t* w3b = w1b + DOUT * 2 * DFEAT;          // 128*256 bf16 =  64 KiB
  uint16_t* emb = w3b + NCLS * DOUT;               // 40000*256 bf16 = 20.5 MB

  const size_t need = ((size_t)(DOUT * 2 * DFEAT + NCLS * DOUT)
                     + (size_t)BNODES * 2 * DFEAT) * sizeof(uint16_t);

  cvt_weights<<<(DOUT * 2 * DFEAT) / 256, 256, 0, stream>>>(W1, W3, w1b, w3b);
  if (ws_size >= need) {
    gather_mean<<<BNODES / TILE, 256, 0, stream>>>(inputs, nbr, feat, emb);
    sage_mlp<<<BNODES / TILE, 256, 0, stream>>>(emb, w1b, b1, w3b, b3,
                                                (float*)d_out);
  } else {
    sage_fused_fb<<<BNODES / TILE, 256, 0, stream>>>(inputs, nbr, feat, w1b, b1,
                                                     w3b, b3, (float*)d_out);
  }
}

// Round 8
// 237.738 us; speedup vs baseline: 1.0774x; 1.0774x over previous
//
#include <hip/hip_runtime.h>
#include <stdint.h>

#define NNODES 200000
#define BNODES 40000
#define DEG    16
#define DFEAT  128
#define DOUT   256
#define NCLS   128
#define TILE   16   // nodes per block (4 per wave)

typedef __attribute__((ext_vector_type(8))) __bf16 bf16x8;
typedef __attribute__((ext_vector_type(4))) float  floatx4;

// round-to-nearest-even fp32 -> bf16 bits
__device__ __forceinline__ uint32_t f2bf(float f) {
  uint32_t x = __float_as_uint(f);
  return ((x + 0x7fffu + ((x >> 16) & 1u)) >> 16) & 0xffffu;
}

__global__ __launch_bounds__(256) void cvt_weights(
    const float* __restrict__ W1, const float* __restrict__ W3,
    uint16_t* __restrict__ w1b, uint16_t* __restrict__ w3b) {
  int i = blockIdx.x * 256 + threadIdx.x;
  if (i < DOUT * 2 * DFEAT) w1b[i] = (uint16_t)f2bf(W1[i]);
  if (i < NCLS * DOUT)      w3b[i] = (uint16_t)f2bf(W3[i]);
}

// ---------------------------------------------------------------------------
// Fused kernel, TILE=16, 8 blocks/CU. Gather phase = r7's proven pure-gather
// structure (full-wave fp32 rows: 64 lanes x float2 = one 512B row per VMEM
// inst, SGPR row base, lane owns dims 2l/2l+1 -> zero cross-lane reduce;
// depth comes from 32 waves/CU). MLP phases overlap into the gather latency
// shadows of co-resident blocks (r1 proved fused >> split: 84.6 vs 126).
// B-fragment loads are grouped per kt so they batch in the vmcnt queue
// instead of load->wait->mfma serial chains (r7-mlp's VGPR=32 pathology).
// ---------------------------------------------------------------------------
__global__ __launch_bounds__(256, 8) void sage_fused(
    const int* __restrict__ inputs, const int* __restrict__ nbr,
    const float* __restrict__ feat,
    const uint16_t* __restrict__ w1b, const float* __restrict__ b1,
    const uint16_t* __restrict__ w3b, const float* __restrict__ b3,
    float* __restrict__ out) {
  // embL (phases 1-2) and lgL (phases 3-4) alias: 16896 B total
  __shared__ __align__(16) unsigned char smemA[TILE * 264 * 2];   // 8448 B
  __shared__ __align__(16) uint16_t hL[TILE][264];                // 8448 B
  uint16_t (*embL)[264] = (uint16_t (*)[264])smemA;
  float    (*lgL)[132]  = (float    (*)[132])smemA;

  const int tid  = threadIdx.x;
  // wave index provably uniform -> neighbor/self id reads become s_loads,
  // every gathered row gets a pure-SGPR base address
  const int w    = __builtin_amdgcn_readfirstlane(tid >> 6);   // wave 0..3
  const int lane = tid & 63;
  const int quad = lane >> 4;
  const int l16  = lane & 15;

  // ---------------- Phase 1: gather + segment-mean -> emb (bf16 in LDS) ----
  {
    const int nodeBase = blockIdx.x * TILE + w * 4;
    const float* fb = feat + lane * 2;        // dims 2l, 2l+1
#pragma unroll
    for (int p = 0; p < 4; ++p) {
      const int node = nodeBase + p;
      const int* nb  = nbr + node * DEG;      // wave-uniform -> s_load
      const int self = inputs[node];
      float2 r[16];
#pragma unroll
      for (int j = 0; j < 16; ++j)
        r[j] = *(const float2*)(fb + (size_t)nb[j] * DFEAT);
      const float2 sv = *(const float2*)(fb + (size_t)self * DFEAT);
      const float sx = (((r[0].x + r[1].x) + (r[2].x + r[3].x)) + ((r[4].x + r[5].x) + (r[6].x + r[7].x)))
                     + (((r[8].x + r[9].x) + (r[10].x + r[11].x)) + ((r[12].x + r[13].x) + (r[14].x + r[15].x)));
      const float sy = (((r[0].y + r[1].y) + (r[2].y + r[3].y)) + ((r[4].y + r[5].y) + (r[6].y + r[7].y)))
                     + (((r[8].y + r[9].y) + (r[10].y + r[11].y)) + ((r[12].y + r[13].y) + (r[14].y + r[15].y)));
      const int row = w * 4 + p;
      *(uint32_t*)&embL[row][lane * 2]         = f2bf(sv.x) | (f2bf(sv.y) << 16);
      *(uint32_t*)&embL[row][DFEAT + lane * 2] = f2bf(sx * 0.0625f) | (f2bf(sy * 0.0625f) << 16);
    }
  }
  __syncthreads();

  const int kq = quad * 8;

  // ---------------- Phase 2: h = relu(emb @ W1^T + b1), bf16 -> LDS --------
  // M=16 rows; wave w owns output cols w*64 .. w*64+63
  {
    floatx4 acc0 = {0.f, 0.f, 0.f, 0.f};
    floatx4 acc1 = {0.f, 0.f, 0.f, 0.f};
    floatx4 acc2 = {0.f, 0.f, 0.f, 0.f};
    floatx4 acc3 = {0.f, 0.f, 0.f, 0.f};
    const uint16_t* wp = w1b + (w * 64 + l16) * 256;
#pragma unroll
    for (int kt = 0; kt < 8; ++kt) {
      const int k0 = kt * 32 + kq;
      const bf16x8 a  = *(const bf16x8*)&embL[l16][k0];
      // group the 4 independent B loads before the MFMAs (batch in vmcnt queue)
      const bf16x8 b0 = *(const bf16x8*)(wp + 0 * 16 * 256 + k0);
      const bf16x8 b1v = *(const bf16x8*)(wp + 1 * 16 * 256 + k0);
      const bf16x8 b2 = *(const bf16x8*)(wp + 2 * 16 * 256 + k0);
      const bf16x8 b3v = *(const bf16x8*)(wp + 3 * 16 * 256 + k0);
      acc0 = __builtin_amdgcn_mfma_f32_16x16x32_bf16(a, b0,  acc0, 0, 0, 0);
      acc1 = __builtin_amdgcn_mfma_f32_16x16x32_bf16(a, b1v, acc1, 0, 0, 0);
      acc2 = __builtin_amdgcn_mfma_f32_16x16x32_bf16(a, b2,  acc2, 0, 0, 0);
      acc3 = __builtin_amdgcn_mfma_f32_16x16x32_bf16(a, b3v, acc3, 0, 0, 0);
    }
    floatx4 accs[4] = {acc0, acc1, acc2, acc3};
#pragma unroll
    for (int ot = 0; ot < 4; ++ot) {
      const int o = w * 64 + ot * 16 + l16;
      const float bias = b1[o];
#pragma unroll
      for (int r = 0; r < 4; ++r) {
        float v = accs[ot][r] + bias;
        v = fmaxf(v, 0.f);
        hL[quad * 4 + r][o] = (uint16_t)f2bf(v);
      }
    }
  }
  __syncthreads();

  // ---------------- Phase 3: logits = h @ W3^T + b3 -> LDS fp32 ------------
  // (writes lgL, aliasing embL -- dead after phase 2's barrier)
  {
    floatx4 acc0 = {0.f, 0.f, 0.f, 0.f};
    floatx4 acc1 = {0.f, 0.f, 0.f, 0.f};
    const uint16_t* wp = w3b + (w * 32 + l16) * 256;
#pragma unroll
    for (int kt = 0; kt < 8; ++kt) {
      const int k0 = kt * 32 + kq;
      const bf16x8 a  = *(const bf16x8*)&hL[l16][k0];
      const bf16x8 b0 = *(const bf16x8*)(wp + 0 * 16 * 256 + k0);
      const bf16x8 b1v = *(const bf16x8*)(wp + 1 * 16 * 256 + k0);
      acc0 = __builtin_amdgcn_mfma_f32_16x16x32_bf16(a, b0,  acc0, 0, 0, 0);
      acc1 = __builtin_amdgcn_mfma_f32_16x16x32_bf16(a, b1v, acc1, 0, 0, 0);
    }
    floatx4 accs[2] = {acc0, acc1};
#pragma unroll
    for (int ct = 0; ct < 2; ++ct) {
      const int c = w * 32 + ct * 16 + l16;
      const float bias = b3[c];
#pragma unroll
      for (int r = 0; r < 4; ++r)
        lgL[quad * 4 + r][c] = accs[ct][r] + bias;
    }
  }
  __syncthreads();

  // ---------------- Phase 4: row L2-normalize + store ----------------------
  {
    const int nr  = tid >> 4;       // node row 0..15
    const int sub = tid & 15;       // 16 threads per row, 8 cols each
    const float* lrow = &lgL[nr][sub * 8];
    float4 v0 = *(const float4*)(lrow + 0);
    float4 v1 = *(const float4*)(lrow + 4);
    float ss = v0.x * v0.x + v0.y * v0.y + v0.z * v0.z + v0.w * v0.w
             + v1.x * v1.x + v1.y * v1.y + v1.z * v1.z + v1.w * v1.w;
    ss += __shfl_xor(ss, 1);
    ss += __shfl_xor(ss, 2);
    ss += __shfl_xor(ss, 4);
    ss += __shfl_xor(ss, 8);
    const float scale = 1.f / fmaxf(sqrtf(ss), 1e-12f);
    v0.x *= scale; v0.y *= scale; v0.z *= scale; v0.w *= scale;
    v1.x *= scale; v1.y *= scale; v1.z *= scale; v1.w *= scale;
    float* op = out + ((size_t)(blockIdx.x * TILE + nr)) * NCLS + sub * 8;
    *(float4*)(op + 0) = v0;
    *(float4*)(op + 4) = v1;
  }
}

extern "C" void kernel_launch(void* const* d_in, const int* in_sizes, int n_in,
                              void* d_out, int out_size, void* d_ws, size_t ws_size,
                              hipStream_t stream) {
  const int*   inputs = (const int*)d_in[0];
  const int*   nbr    = (const int*)d_in[1];
  // d_in[2] segment_ids: regular repeat(arange(B), 16) -> implicit, unused
  const float* feat   = (const float*)d_in[3];
  const float* W1     = (const float*)d_in[4];
  const float* b1     = (const float*)d_in[5];
  const float* W3     = (const float*)d_in[6];
  const float* b3     = (const float*)d_in[7];

  uint16_t* w1b = (uint16_t*)d_ws;                 // 256*256 bf16 = 128 KiB
  uint16_t* w3b = w1b + DOUT * 2 * DFEAT;          // 128*256 bf16 =  64 KiB

  cvt_weights<<<(DOUT * 2 * DFEAT) / 256, 256, 0, stream>>>(W1, W3, w1b, w3b);
  sage_fused<<<BNODES / TILE, 256, 0, stream>>>(inputs, nbr, feat, w1b, b1,
                                                w3b, b3, (float*)d_out);
}

// Round 9
// 215.916 us; speedup vs baseline: 1.1863x; 1.1011x over previous
//
#include <hip/hip_runtime.h>
#include <stdint.h>

#define NNODES 200000
#define BNODES 40000
#define DEG    16
#define DFEAT  128
#define DOUT   256
#define NCLS   128
#define TILE   32   // nodes per block (8 per wave)

typedef __attribute__((ext_vector_type(8))) __bf16 bf16x8;
typedef __attribute__((ext_vector_type(4))) float  floatx4;

// round-to-nearest-even fp32 -> bf16 bits
__device__ __forceinline__ uint32_t f2bf(float f) {
  uint32_t x = __float_as_uint(f);
  return ((x + 0x7fffu + ((x >> 16) & 1u)) >> 16) & 0xffffu;
}

__global__ __launch_bounds__(256) void cvt_weights(
    const float* __restrict__ W1, const float* __restrict__ W3,
    uint16_t* __restrict__ w1b, uint16_t* __restrict__ w3b) {
  int i = blockIdx.x * 256 + threadIdx.x;
  if (i < DOUT * 2 * DFEAT) w1b[i] = (uint16_t)f2bf(W1[i]);
  if (i < NCLS * DOUT)      w3b[i] = (uint16_t)f2bf(W3[i]);
}

// ---------------------------------------------------------------------------
// Fused kernel. The one untested cell of the {addressing} x {register budget}
// matrix: full-wave SGPR-base rows (zero per-lane address VGPRs -- r4/r7/r8's
// structure) UNDER launch_bounds(256,4)'s 128-VGPR budget (r1/r3's budget,
// which the compiler honors with 64+ VGPRs). 2-node batches = 34 full-wave
// float2 loads (68 result VGPRs) in flight per wave -- ~3x r1's depth.
// TILE=32, 33.8KB LDS -> 4 blocks/CU, same as the 84.6us r1 champion.
// ---------------------------------------------------------------------------
__global__ __launch_bounds__(256, 4) void sage_fused(
    const int* __restrict__ inputs, const int* __restrict__ nbr,
    const float* __restrict__ feat,
    const uint16_t* __restrict__ w1b, const float* __restrict__ b1,
    const uint16_t* __restrict__ w3b, const float* __restrict__ b3,
    float* __restrict__ out) {
  // embL (phases 1-2) and lgL (phases 3-4) alias: 33792 B total => 4 blocks/CU
  __shared__ __align__(16) unsigned char smemA[TILE * 264 * 2];   // 16896 B
  __shared__ __align__(16) uint16_t hL[TILE][264];                // 16896 B
  uint16_t (*embL)[264] = (uint16_t (*)[264])smemA;
  float    (*lgL)[132]  = (float    (*)[132])smemA;

  const int tid  = threadIdx.x;
  // wave index provably uniform -> neighbor/self id reads become s_loads and
  // every gathered row gets a pure-SGPR base address (no per-lane addr VGPRs)
  const int w    = __builtin_amdgcn_readfirstlane(tid >> 6);   // wave 0..3
  const int lane = tid & 63;
  const int quad = lane >> 4;
  const int l16  = lane & 15;

  // ---------------- Phase 1: gather + segment-mean -> emb (bf16 in LDS) ----
  // Full-wave row loads: 64 lanes x float2 = one 512B fp32 row per VMEM
  // instruction. Lane owns dims 2l,2l+1 -> zero cross-lane reduction.
  // 2-node batches keep 34 rows (~17KB) in flight per wave.
  {
    const int nodeBase = blockIdx.x * TILE + w * 8;
    const float* fb = feat + lane * 2;        // dims 2l, 2l+1
#pragma unroll
    for (int pp = 0; pp < 8; pp += 2) {
      const int nA = nodeBase + pp, nB = nodeBase + pp + 1;
      const int* nbA = nbr + nA * DEG;        // wave-uniform -> s_load
      const int* nbB = nbr + nB * DEG;
      const int sA = inputs[nA], sB = inputs[nB];
      float2 rA[16], rB[16];
#pragma unroll
      for (int j = 0; j < 16; ++j)
        rA[j] = *(const float2*)(fb + (size_t)nbA[j] * DFEAT);
      const float2 svA = *(const float2*)(fb + (size_t)sA * DFEAT);
#pragma unroll
      for (int j = 0; j < 16; ++j)
        rB[j] = *(const float2*)(fb + (size_t)nbB[j] * DFEAT);
      const float2 svB = *(const float2*)(fb + (size_t)sB * DFEAT);
      // ---- reduce + write A --------------------------------------------
      {
        const float sx = (((rA[0].x + rA[1].x) + (rA[2].x + rA[3].x)) + ((rA[4].x + rA[5].x) + (rA[6].x + rA[7].x)))
                       + (((rA[8].x + rA[9].x) + (rA[10].x + rA[11].x)) + ((rA[12].x + rA[13].x) + (rA[14].x + rA[15].x)));
        const float sy = (((rA[0].y + rA[1].y) + (rA[2].y + rA[3].y)) + ((rA[4].y + rA[5].y) + (rA[6].y + rA[7].y)))
                       + (((rA[8].y + rA[9].y) + (rA[10].y + rA[11].y)) + ((rA[12].y + rA[13].y) + (rA[14].y + rA[15].y)));
        const int row = w * 8 + pp;
        *(uint32_t*)&embL[row][lane * 2]         = f2bf(svA.x) | (f2bf(svA.y) << 16);
        *(uint32_t*)&embL[row][DFEAT + lane * 2] = f2bf(sx * 0.0625f) | (f2bf(sy * 0.0625f) << 16);
      }
      // ---- reduce + write B --------------------------------------------
      {
        const float sx = (((rB[0].x + rB[1].x) + (rB[2].x + rB[3].x)) + ((rB[4].x + rB[5].x) + (rB[6].x + rB[7].x)))
                       + (((rB[8].x + rB[9].x) + (rB[10].x + rB[11].x)) + ((rB[12].x + rB[13].x) + (rB[14].x + rB[15].x)));
        const float sy = (((rB[0].y + rB[1].y) + (rB[2].y + rB[3].y)) + ((rB[4].y + rB[5].y) + (rB[6].y + rB[7].y)))
                       + (((rB[8].y + rB[9].y) + (rB[10].y + rB[11].y)) + ((rB[12].y + rB[13].y) + (rB[14].y + rB[15].y)));
        const int row = w * 8 + pp + 1;
        *(uint32_t*)&embL[row][lane * 2]         = f2bf(svB.x) | (f2bf(svB.y) << 16);
        *(uint32_t*)&embL[row][DFEAT + lane * 2] = f2bf(sx * 0.0625f) | (f2bf(sy * 0.0625f) << 16);
      }
    }
  }
  __syncthreads();

  const int kq = quad * 8;

  // ---------------- Phase 2: h = relu(emb @ W1^T + b1), bf16 -> LDS --------
  {
    floatx4 acc[2][4];
#pragma unroll
    for (int mt = 0; mt < 2; ++mt)
#pragma unroll
      for (int ot = 0; ot < 4; ++ot) {
        floatx4 z = {0.f, 0.f, 0.f, 0.f};
        acc[mt][ot] = z;
      }
#pragma unroll
    for (int kt = 0; kt < 8; ++kt) {
      const int k0 = kt * 32 + kq;
      const bf16x8 a0 = *(const bf16x8*)&embL[l16][k0];
      const bf16x8 a1 = *(const bf16x8*)&embL[16 + l16][k0];
#pragma unroll
      for (int ot = 0; ot < 4; ++ot) {
        const int o = (w * 4 + ot) * 16 + l16;
        const bf16x8 b = *(const bf16x8*)(w1b + o * 256 + k0);
        acc[0][ot] = __builtin_amdgcn_mfma_f32_16x16x32_bf16(a0, b, acc[0][ot], 0, 0, 0);
        acc[1][ot] = __builtin_amdgcn_mfma_f32_16x16x32_bf16(a1, b, acc[1][ot], 0, 0, 0);
      }
    }
#pragma unroll
    for (int ot = 0; ot < 4; ++ot) {
      const int o = (w * 4 + ot) * 16 + l16;
      const float bias = b1[o];
#pragma unroll
      for (int mt = 0; mt < 2; ++mt)
#pragma unroll
        for (int r = 0; r < 4; ++r) {
          float v = acc[mt][ot][r] + bias;
          v = fmaxf(v, 0.f);
          hL[mt * 16 + quad * 4 + r][o] = (uint16_t)f2bf(v);
        }
    }
  }
  __syncthreads();

  // ---------------- Phase 3: logits = h @ W3^T + b3 -> LDS fp32 ------------
  // (writes lgL, aliasing embL -- dead after phase 2's barrier)
  {
    floatx4 acc2[2][2];
#pragma unroll
    for (int mt = 0; mt < 2; ++mt)
#pragma unroll
      for (int ct = 0; ct < 2; ++ct) {
        floatx4 z = {0.f, 0.f, 0.f, 0.f};
        acc2[mt][ct] = z;
      }
#pragma unroll
    for (int kt = 0; kt < 8; ++kt) {
      const int k0 = kt * 32 + kq;
      const bf16x8 a0 = *(const bf16x8*)&hL[l16][k0];
      const bf16x8 a1 = *(const bf16x8*)&hL[16 + l16][k0];
#pragma unroll
      for (int ct = 0; ct < 2; ++ct) {
        const int c = (w * 2 + ct) * 16 + l16;
        const bf16x8 b = *(const bf16x8*)(w3b + c * 256 + k0);
        acc2[0][ct] = __builtin_amdgcn_mfma_f32_16x16x32_bf16(a0, b, acc2[0][ct], 0, 0, 0);
        acc2[1][ct] = __builtin_amdgcn_mfma_f32_16x16x32_bf16(a1, b, acc2[1][ct], 0, 0, 0);
      }
    }
#pragma unroll
    for (int ct = 0; ct < 2; ++ct) {
      const int c = (w * 2 + ct) * 16 + l16;
      const float bias = b3[c];
#pragma unroll
      for (int mt = 0; mt < 2; ++mt)
#pragma unroll
        for (int r = 0; r < 4; ++r)
          lgL[mt * 16 + quad * 4 + r][c] = acc2[mt][ct][r] + bias;
    }
  }
  __syncthreads();

  // ---------------- Phase 4: row L2-normalize + store ----------------------
  {
    const int nr  = tid >> 3;       // node row 0..31
    const int sub = tid & 7;        // 8 threads per row, 16 cols each
    const float* lrow = &lgL[nr][sub * 16];
    float4 v0 = *(const float4*)(lrow + 0);
    float4 v1 = *(const float4*)(lrow + 4);
    float4 v2 = *(const float4*)(lrow + 8);
    float4 v3 = *(const float4*)(lrow + 12);
    float ss = v0.x * v0.x + v0.y * v0.y + v0.z * v0.z + v0.w * v0.w
             + v1.x * v1.x + v1.y * v1.y + v1.z * v1.z + v1.w * v1.w
             + v2.x * v2.x + v2.y * v2.y + v2.z * v2.z + v2.w * v2.w
             + v3.x * v3.x + v3.y * v3.y + v3.z * v3.z + v3.w * v3.w;
    ss += __shfl_xor(ss, 1);
    ss += __shfl_xor(ss, 2);
    ss += __shfl_xor(ss, 4);
    const float scale = 1.f / fmaxf(sqrtf(ss), 1e-12f);
    v0.x *= scale; v0.y *= scale; v0.z *= scale; v0.w *= scale;
    v1.x *= scale; v1.y *= scale; v1.z *= scale; v1.w *= scale;
    v2.x *= scale; v2.y *= scale; v2.z *= scale; v2.w *= scale;
    v3.x *= scale; v3.y *= scale; v3.z *= scale; v3.w *= scale;
    float* op = out + ((size_t)(blockIdx.x * TILE + nr)) * NCLS + sub * 16;
    *(float4*)(op + 0)  = v0;
    *(float4*)(op + 4)  = v1;
    *(float4*)(op + 8)  = v2;
    *(float4*)(op + 12) = v3;
  }
}

extern "C" void kernel_launch(void* const* d_in, const int* in_sizes, int n_in,
                              void* d_out, int out_size, void* d_ws, size_t ws_size,
                              hipStream_t stream) {
  const int*   inputs = (const int*)d_in[0];
  const int*   nbr    = (const int*)d_in[1];
  // d_in[2] segment_ids: regular repeat(arange(B), 16) -> implicit, unused
  const float* feat   = (const float*)d_in[3];
  const float* W1     = (const float*)d_in[4];
  const float* b1     = (const float*)d_in[5];
  const float* W3     = (const float*)d_in[6];
  const float* b3     = (const float*)d_in[7];

  uint16_t* w1b = (uint16_t*)d_ws;                 // 256*256 bf16
  uint16_t* w3b = w1b + DOUT * 2 * DFEAT;          // 128*256 bf16 (total 192 KiB ws)

  cvt_weights<<<(DOUT * 2 * DFEAT) / 256, 256, 0, stream>>>(W1, W3, w1b, w3b);
  sage_fused<<<BNODES / TILE, 256, 0, stream>>>(inputs, nbr, feat, w1b, b1,
                                                w3b, b3, (float*)d_out);
}